// Round 5
// baseline (402.408 us; speedup 1.0000x reference)
//
#include <hip/hip_runtime.h>

#define NNODES 40000
#define NEDGES 640000
#define DIN 128
#define DHID 256
#define DOUT 47
#define NCNT 40960
#define NPART (NCNT / 256)

typedef __attribute__((ext_vector_type(8))) short short8;
typedef __attribute__((ext_vector_type(4))) float f32x4;

__device__ inline float bf2f(unsigned short u) {
    union { unsigned int i; float f; } c; c.i = ((unsigned int)u) << 16; return c.f;
}
__device__ inline unsigned short f2bf(float f) {
    union { float f; unsigned int i; } c; c.f = f;
    unsigned int x = c.i;
    x += 0x7fff + ((x >> 16) & 1);  // RNE
    return (unsigned short)(x >> 16);
}

// ---------------- CSR build ----------------
__global__ void hist_kernel(const int* __restrict__ dst, int* __restrict__ cnt) {
    int t = blockIdx.x * blockDim.x + threadIdx.x;
    if (t < NEDGES) atomicAdd(&cnt[dst[t]], 1);
}

__global__ void part_kernel(const int* __restrict__ cnt, int* __restrict__ part) {
    int b = blockIdx.x, t = threadIdx.x;
    int v = cnt[b * 256 + t];
#pragma unroll
    for (int off = 32; off > 0; off >>= 1) v += __shfl_down(v, off);
    __shared__ int ws[4];
    if ((t & 63) == 0) ws[t >> 6] = v;
    __syncthreads();
    if (t == 0) part[b] = ws[0] + ws[1] + ws[2] + ws[3];
}

__global__ void scanpart_kernel(const int* __restrict__ part, int* __restrict__ partoff) {
    __shared__ int sh[256];
    int t = threadIdx.x;
    int v = (t < NPART) ? part[t] : 0;
    sh[t] = v;
    __syncthreads();
    for (int off = 1; off < 256; off <<= 1) {
        int add = (t >= off) ? sh[t - off] : 0;
        __syncthreads();
        sh[t] += add;
        __syncthreads();
    }
    if (t < NPART) partoff[t] = sh[t] - v;
}

__global__ void writeptr_kernel(const int* __restrict__ cnt, const int* __restrict__ partoff,
                                int* __restrict__ rowptr) {
    __shared__ int sh[256];
    int b = blockIdx.x, t = threadIdx.x;
    int idx = b * 256 + t;
    int v = cnt[idx];
    sh[t] = v;
    __syncthreads();
    for (int off = 1; off < 256; off <<= 1) {
        int add = (t >= off) ? sh[t - off] : 0;
        __syncthreads();
        sh[t] += add;
        __syncthreads();
    }
    rowptr[idx] = partoff[b] + sh[t] - v;
}

// eidx stored as ushort (NNODES < 65536)
__global__ void fill_kernel(const int* __restrict__ src, const int* __restrict__ dst,
                            const int* __restrict__ rowptr, int* __restrict__ fill,
                            unsigned short* __restrict__ eidx) {
    int e = blockIdx.x * blockDim.x + threadIdx.x;
    if (e < NEDGES) {
        int d = dst[e];
        int pos = rowptr[d] + atomicAdd(&fill[d], 1);
        eidx[pos] = (unsigned short)src[e];
    }
}

// ---------------- conversions ----------------
__global__ void f32_to_bf16x4_kernel(const float4* __restrict__ in, ushort4* __restrict__ out, int n4) {
    int t = blockIdx.x * blockDim.x + threadIdx.x;
    if (t < n4) {
        float4 v = in[t];
        ushort4 r;
        r.x = f2bf(v.x); r.y = f2bf(v.y); r.z = f2bf(v.z); r.w = f2bf(v.w);
        out[t] = r;
    }
}

__global__ void conv_wt_kernel(const float* __restrict__ W, unsigned short* __restrict__ Wt, int K, int N) {
    int t = blockIdx.x * blockDim.x + threadIdx.x;
    if (t < K * N) {
        int k = t / N, n = t - k * N;
        Wt[(size_t)n * K + k] = f2bf(W[t]);
    }
}

// W3 [512][47] -> Wt3 [94][256]
__global__ void conv_wt3_kernel(const float* __restrict__ W3, unsigned short* __restrict__ Wt) {
    int t = blockIdx.x * blockDim.x + threadIdx.x;
    if (t < 94 * 256) {
        int n = t >> 8, k = t & 255;
        float v = (n < 47) ? W3[(size_t)k * DOUT + n]
                           : W3[(size_t)(k + DHID) * DOUT + (n - 47)];
        Wt[t] = f2bf(v);
    }
}

// ---------------- XCD-sliced mean aggregation ----------------
// Feature dim split into NCH = D/32 chunks of 32 features (64B slice rows).
// gridDim.x = NCH; chunk c = blockIdx.x. Dispatch round-robin pins
// (bx + NCH*by) % 8 so each XCD sees one slice; slice (2.56 MB) + ushort eidx
// (1.25 MB, nt-loaded) fit the 4 MB XCD L2 -> gathers become L2 hits.
// Wave: 4 edges/load-instruction (16 lanes x ushort2), ILP-8.
template <int D>
__global__ void agg_sliced_kernel(const unsigned short* __restrict__ h,
                                  const int* __restrict__ rowptr,
                                  const unsigned short* __restrict__ eidx,
                                  unsigned short* __restrict__ mean) {
    const int c = blockIdx.x;                       // feature chunk
    const int node = blockIdx.y * 16 + (threadIdx.x >> 6);
    if (node >= NNODES) return;
    const int lane = threadIdx.x & 63;
    const int esub = lane >> 4;                     // 0..3 (edge sub-slot)
    const int f2 = lane & 15;                       // feature pair
    const int beg = __builtin_nontemporal_load(rowptr + node);
    const int end = __builtin_nontemporal_load(rowptr + node + 1);
    const unsigned short* hp = h + c * 32 + f2 * 2;

    float ax = 0.0f, ay = 0.0f;
    int j = beg;
    for (; j + 8 <= end; j += 8) {
        int s0 = (int)__builtin_nontemporal_load(eidx + j + esub);
        int s1 = (int)__builtin_nontemporal_load(eidx + j + 4 + esub);
        ushort2 v0 = *(const ushort2*)(hp + (size_t)s0 * D);
        ushort2 v1 = *(const ushort2*)(hp + (size_t)s1 * D);
        ax += bf2f(v0.x) + bf2f(v1.x);
        ay += bf2f(v0.y) + bf2f(v1.y);
    }
    for (; j + 4 <= end; j += 4) {
        int s0 = (int)__builtin_nontemporal_load(eidx + j + esub);
        ushort2 v0 = *(const ushort2*)(hp + (size_t)s0 * D);
        ax += bf2f(v0.x);
        ay += bf2f(v0.y);
    }
    int rem = end - j;  // 0..3
    if (rem > 0) {
        int jj = j + (esub < rem ? esub : 0);
        int s0 = (int)__builtin_nontemporal_load(eidx + jj);
        ushort2 v0 = *(const ushort2*)(hp + (size_t)s0 * D);
        if (esub < rem) { ax += bf2f(v0.x); ay += bf2f(v0.y); }
    }
    // reduce over esub (lane bits 4,5)
    ax += __shfl_xor(ax, 16); ay += __shfl_xor(ay, 16);
    ax += __shfl_xor(ax, 32); ay += __shfl_xor(ay, 32);
    if (lane < 16) {
        float inv = (end > beg) ? 1.0f / (float)(end - beg) : 0.0f;
        unsigned int rv = (unsigned int)f2bf(ax * inv) | ((unsigned int)f2bf(ay * inv) << 16);
        __builtin_nontemporal_store(rv, (unsigned int*)(mean + (size_t)node * D + c * 32 + lane * 2));
    }
}

// ---------------- layer-3 P aggregation (P = 3.84 MB, fits every L2) ----------------
__global__ void agg_p_kernel(const unsigned short* __restrict__ P,
                             const int* __restrict__ rowptr,
                             const unsigned short* __restrict__ eidx,
                             float* __restrict__ out) {
    const int node = blockIdx.x * (blockDim.x >> 6) + (threadIdx.x >> 6);
    if (node >= NNODES) return;
    const int lane = threadIdx.x & 63;
    const int beg = rowptr[node], end = rowptr[node + 1];
    const bool active = lane < 48;
    const int lc = active ? lane : 0;

    float acc = 0.0f;
    for (int base = beg; base < end; base += 64) {
        int n = min(64, end - base);
        int myidx = (base + lane < end) ? (int)__builtin_nontemporal_load(eidx + base + lane) : 0;
        int j = 0;
        for (; j + 4 <= n; j += 4) {
            int s0 = __shfl(myidx, j);
            int s1 = __shfl(myidx, j + 1);
            int s2 = __shfl(myidx, j + 2);
            int s3 = __shfl(myidx, j + 3);
            if (active) {
                float a = bf2f(P[(size_t)s0 * 48 + lc]) + bf2f(P[(size_t)s1 * 48 + lc]);
                float b = bf2f(P[(size_t)s2 * 48 + lc]) + bf2f(P[(size_t)s3 * 48 + lc]);
                acc += a + b;
            }
        }
        for (; j < n; ++j) {
            int s = __shfl(myidx, j);
            if (active) acc += bf2f(P[(size_t)s * 48 + lc]);
        }
    }
    if (lane < 47 && end > beg) {
        out[(size_t)node * DOUT + lane] += acc / (float)(end - beg);
    }
}

// ---------------- bf16 MFMA GEMM ----------------
// MODE 0: A = [H | Mn] virtual concat, K = 2*d, out bf16 [M][N] relu+bias.
// MODE 2: A = H row stride K (d = K/2), dual out: col<47 -> f32 out + bias;
//         col in [47,94) -> Pout bf16 [M][48].
template <int MODE>
__launch_bounds__(256, 2)
__global__ void gemm_mfma_kernel(const unsigned short* __restrict__ H,
                                 const unsigned short* __restrict__ Mn,
                                 const unsigned short* __restrict__ Wt,
                                 const float* __restrict__ bias,
                                 void* __restrict__ outp,
                                 unsigned short* __restrict__ Pout,
                                 int d, int N) {
    const int K = 2 * d;
    __shared__ uint4 AsB[128 * 4];
    __shared__ uint4 BsB[128 * 4];

    const int tid = threadIdx.x;
    const int lane = tid & 63;
    const int wid = tid >> 6;
    const int wr = wid >> 1, wc = wid & 1;
    const int row0 = blockIdx.x * 128;
    const int col0 = blockIdx.y * 128;

    const int sr = tid >> 1;
    const int sh = tid & 1;
    const int gar = min(row0 + sr, NNODES - 1);
    const int gbr = min(col0 + sr, N - 1);
    const int ssw = (sr >> 1) & 3;

    f32x4 acc[4][4];
#pragma unroll
    for (int m = 0; m < 4; ++m)
#pragma unroll
        for (int n = 0; n < 4; ++n) {
            f32x4 z = {0.0f, 0.0f, 0.0f, 0.0f};
            acc[m][n] = z;
        }

    for (int k0 = 0; k0 < K; k0 += 32) {
        {
            int kb = k0 + sh * 16;
            const unsigned short* p;
            if (MODE == 2) {
                p = H + (size_t)gar * K + kb;
            } else {
                p = (kb < d) ? (H + (size_t)gar * d + kb)
                             : (Mn + (size_t)gar * d + (kb - d));
            }
            uint4 v0 = *(const uint4*)p;
            uint4 v1 = *(const uint4*)(p + 8);
            AsB[sr * 4 + ((2 * sh) ^ ssw)]     = v0;
            AsB[sr * 4 + ((2 * sh + 1) ^ ssw)] = v1;
        }
        {
            const unsigned short* p = Wt + (size_t)gbr * K + k0 + sh * 16;
            uint4 v0 = *(const uint4*)p;
            uint4 v1 = *(const uint4*)(p + 8);
            BsB[sr * 4 + ((2 * sh) ^ ssw)]     = v0;
            BsB[sr * 4 + ((2 * sh + 1) ^ ssw)] = v1;
        }
        __syncthreads();

        short8 af[4], bfr[4];
        const int fr = lane & 15;
        const int slot = lane >> 4;
#pragma unroll
        for (int m = 0; m < 4; ++m) {
            int r = wr * 64 + m * 16 + fr;
            union { uint4 u; short8 s; } cc;
            cc.u = AsB[r * 4 + (slot ^ ((r >> 1) & 3))];
            af[m] = cc.s;
        }
#pragma unroll
        for (int n = 0; n < 4; ++n) {
            int r = wc * 64 + n * 16 + fr;
            union { uint4 u; short8 s; } cc;
            cc.u = BsB[r * 4 + (slot ^ ((r >> 1) & 3))];
            bfr[n] = cc.s;
        }
#pragma unroll
        for (int m = 0; m < 4; ++m)
#pragma unroll
            for (int n = 0; n < 4; ++n)
                acc[m][n] = __builtin_amdgcn_mfma_f32_16x16x32_bf16(af[m], bfr[n], acc[m][n], 0, 0, 0);
        __syncthreads();
    }

#pragma unroll
    for (int m = 0; m < 4; ++m) {
#pragma unroll
        for (int n = 0; n < 4; ++n) {
            int col = col0 + wc * 64 + n * 16 + (lane & 15);
            if (col >= N) continue;
            float bv = (MODE == 0) ? bias[col] : ((col < 47) ? bias[col] : 0.0f);
#pragma unroll
            for (int q = 0; q < 4; ++q) {
                int row = row0 + wr * 64 + m * 16 + (lane >> 4) * 4 + q;
                if (row < NNODES) {
                    float v = acc[m][n][q] + bv;
                    if (MODE == 0) {
                        v = fmaxf(v, 0.0f);
                        ((unsigned short*)outp)[(size_t)row * N + col] = f2bf(v);
                    } else {
                        if (col < 47) ((float*)outp)[(size_t)row * DOUT + col] = v;
                        else Pout[(size_t)row * 48 + (col - 47)] = f2bf(v);
                    }
                }
            }
        }
    }
}

extern "C" void kernel_launch(void* const* d_in, const int* in_sizes, int n_in,
                              void* d_out, int out_size, void* d_ws, size_t ws_size,
                              hipStream_t stream) {
    const float* x  = (const float*)d_in[0];
    const float* W1 = (const float*)d_in[1];
    const float* b1 = (const float*)d_in[2];
    const float* W2 = (const float*)d_in[3];
    const float* b2 = (const float*)d_in[4];
    const float* W3 = (const float*)d_in[5];
    const float* b3 = (const float*)d_in[6];
    const int* src  = (const int*)d_in[7];
    const int* dst  = (const int*)d_in[8];
    float* out = (float*)d_out;

    int* rowptr  = (int*)d_ws;                          // NCNT ints
    unsigned short* eidx = (unsigned short*)(rowptr + NCNT);  // NEDGES ushort
    int* cnt     = (int*)(eidx + NEDGES);               // NCNT
    int* fill    = cnt + NCNT;                          // NCNT
    int* part    = fill + NCNT;                         // 256
    int* partoff = part + 256;                          // 256
    unsigned short* xbf  = (unsigned short*)(partoff + 256);
    unsigned short* h1   = xbf + (size_t)NNODES * DIN;
    unsigned short* h2   = h1 + (size_t)NNODES * DHID;
    unsigned short* mean = h2 + (size_t)NNODES * DHID;
    unsigned short* wt1  = mean + (size_t)NNODES * DHID;
    unsigned short* wt2  = wt1 + 2 * DIN * DHID;
    unsigned short* wt3  = wt2 + 2 * DHID * DHID;
    unsigned short* P    = mean;  // layer-3 reuse

    // ---- CSR build ----
    hipMemsetAsync(cnt, 0, 2 * NCNT * sizeof(int), stream);
    hist_kernel<<<(NEDGES + 255) / 256, 256, 0, stream>>>(dst, cnt);
    part_kernel<<<NPART, 256, 0, stream>>>(cnt, part);
    scanpart_kernel<<<1, 256, 0, stream>>>(part, partoff);
    writeptr_kernel<<<NPART, 256, 0, stream>>>(cnt, partoff, rowptr);
    fill_kernel<<<(NEDGES + 255) / 256, 256, 0, stream>>>(src, dst, rowptr, fill, eidx);

    // ---- conversions ----
    f32_to_bf16x4_kernel<<<(NNODES * DIN / 4 + 255) / 256, 256, 0, stream>>>(
        (const float4*)x, (ushort4*)xbf, NNODES * DIN / 4);
    conv_wt_kernel<<<(2 * DIN * DHID + 255) / 256, 256, 0, stream>>>(W1, wt1, 2 * DIN, DHID);
    conv_wt_kernel<<<(2 * DHID * DHID + 255) / 256, 256, 0, stream>>>(W2, wt2, 2 * DHID, DHID);
    conv_wt3_kernel<<<(94 * 256 + 255) / 256, 256, 0, stream>>>(W3, wt3);

    const int MB = (NNODES + 127) / 128;  // 313
    const int NGRP = (NNODES + 15) / 16;  // 2500

    // ---- layer 1: d=128 -> 256
    {
        dim3 grid(DIN / 32, NGRP);  // 4 chunks
        agg_sliced_kernel<DIN><<<grid, 1024, 0, stream>>>(xbf, rowptr, eidx, mean);
    }
    {
        dim3 grid(MB, 2);
        gemm_mfma_kernel<0><<<grid, 256, 0, stream>>>(xbf, mean, wt1, b1, h1, nullptr, DIN, DHID);
    }

    // ---- layer 2: d=256 -> 256
    {
        dim3 grid(DHID / 32, NGRP);  // 8 chunks
        agg_sliced_kernel<DHID><<<grid, 1024, 0, stream>>>(h1, rowptr, eidx, mean);
    }
    {
        dim3 grid(MB, 2);
        gemm_mfma_kernel<0><<<grid, 256, 0, stream>>>(h1, mean, wt2, b2, h2, nullptr, DHID, DHID);
    }

    // ---- layer 3: dual GEMM then P-aggregate
    {
        dim3 grid(MB, 1);
        gemm_mfma_kernel<2><<<grid, 256, 0, stream>>>(h2, h2, wt3, b3, out, P, DHID / 2, 94);
    }
    agg_p_kernel<<<NNODES / 4, 256, 0, stream>>>(P, rowptr, eidx, out);
}

// Round 6
// 236.326 us; speedup vs baseline: 1.7028x; 1.7028x over previous
//
#include <hip/hip_runtime.h>

#define NNODES 40000
#define NEDGES 640000
#define DIN 128
#define DHID 256
#define DOUT 47
#define NCNT 40960
#define NPART (NCNT / 256)

typedef __attribute__((ext_vector_type(8))) short short8;
typedef __attribute__((ext_vector_type(4))) float f32x4;

__device__ inline float bf2f(unsigned short u) {
    union { unsigned int i; float f; } c; c.i = ((unsigned int)u) << 16; return c.f;
}
__device__ inline unsigned short f2bf(float f) {
    union { float f; unsigned int i; } c; c.f = f;
    unsigned int x = c.i;
    x += 0x7fff + ((x >> 16) & 1);  // RNE
    return (unsigned short)(x >> 16);
}

// ---------------- CSR build ----------------
__global__ void hist_kernel(const int* __restrict__ dst, int* __restrict__ cnt) {
    int t = blockIdx.x * blockDim.x + threadIdx.x;
    if (t < NEDGES) atomicAdd(&cnt[dst[t]], 1);
}

__global__ void part_kernel(const int* __restrict__ cnt, int* __restrict__ part) {
    int b = blockIdx.x, t = threadIdx.x;
    int v = cnt[b * 256 + t];
#pragma unroll
    for (int off = 32; off > 0; off >>= 1) v += __shfl_down(v, off);
    __shared__ int ws[4];
    if ((t & 63) == 0) ws[t >> 6] = v;
    __syncthreads();
    if (t == 0) part[b] = ws[0] + ws[1] + ws[2] + ws[3];
}

__global__ void scanpart_kernel(const int* __restrict__ part, int* __restrict__ partoff) {
    __shared__ int sh[256];
    int t = threadIdx.x;
    int v = (t < NPART) ? part[t] : 0;
    sh[t] = v;
    __syncthreads();
    for (int off = 1; off < 256; off <<= 1) {
        int add = (t >= off) ? sh[t - off] : 0;
        __syncthreads();
        sh[t] += add;
        __syncthreads();
    }
    if (t < NPART) partoff[t] = sh[t] - v;
}

__global__ void writeptr_kernel(const int* __restrict__ cnt, const int* __restrict__ partoff,
                                int* __restrict__ rowptr) {
    __shared__ int sh[256];
    int b = blockIdx.x, t = threadIdx.x;
    int idx = b * 256 + t;
    int v = cnt[idx];
    sh[t] = v;
    __syncthreads();
    for (int off = 1; off < 256; off <<= 1) {
        int add = (t >= off) ? sh[t - off] : 0;
        __syncthreads();
        sh[t] += add;
        __syncthreads();
    }
    rowptr[idx] = partoff[b] + sh[t] - v;
}

// eidx stored as ushort (NNODES < 65536)
__global__ void fill_kernel(const int* __restrict__ src, const int* __restrict__ dst,
                            const int* __restrict__ rowptr, int* __restrict__ fill,
                            unsigned short* __restrict__ eidx) {
    int e = blockIdx.x * blockDim.x + threadIdx.x;
    if (e < NEDGES) {
        int d = dst[e];
        int pos = rowptr[d] + atomicAdd(&fill[d], 1);
        eidx[pos] = (unsigned short)src[e];
    }
}

// ---------------- conversions ----------------
__global__ void f32_to_bf16x4_kernel(const float4* __restrict__ in, ushort4* __restrict__ out, int n4) {
    int t = blockIdx.x * blockDim.x + threadIdx.x;
    if (t < n4) {
        float4 v = in[t];
        ushort4 r;
        r.x = f2bf(v.x); r.y = f2bf(v.y); r.z = f2bf(v.z); r.w = f2bf(v.w);
        out[t] = r;
    }
}

__global__ void conv_wt_kernel(const float* __restrict__ W, unsigned short* __restrict__ Wt, int K, int N) {
    int t = blockIdx.x * blockDim.x + threadIdx.x;
    if (t < K * N) {
        int k = t / N, n = t - k * N;
        Wt[(size_t)n * K + k] = f2bf(W[t]);
    }
}

// W3 [512][47] -> Wt3 [94][256]
__global__ void conv_wt3_kernel(const float* __restrict__ W3, unsigned short* __restrict__ Wt) {
    int t = blockIdx.x * blockDim.x + threadIdx.x;
    if (t < 94 * 256) {
        int n = t >> 8, k = t & 255;
        float v = (n < 47) ? W3[(size_t)k * DOUT + n]
                           : W3[(size_t)(k + DHID) * DOUT + (n - 47)];
        Wt[t] = f2bf(v);
    }
}

// ---------------- mean aggregation (bf16, wave/node, 8x ILP) ----------------
template <int D>
__global__ void agg_bf16_kernel(const unsigned short* __restrict__ h,
                                const int* __restrict__ rowptr,
                                const unsigned short* __restrict__ eidx,
                                unsigned short* __restrict__ mean) {
    constexpr int VPL = D / 64;  // 2 (D=128) or 4 (D=256)
    const int node = blockIdx.x * (blockDim.x >> 6) + (threadIdx.x >> 6);
    if (node >= NNODES) return;
    const int lane = threadIdx.x & 63;
    const int beg = rowptr[node], end = rowptr[node + 1];
    const unsigned short* hp = h + lane * VPL;

    float acc[VPL];
#pragma unroll
    for (int i = 0; i < VPL; ++i) acc[i] = 0.0f;

    for (int base = beg; base < end; base += 64) {
        int n = min(64, end - base);
        int myidx = (base + lane < end) ? (int)eidx[base + lane] : 0;
        int j = 0;
        for (; j + 8 <= n; j += 8) {
            int s[8];
#pragma unroll
            for (int u = 0; u < 8; ++u) s[u] = __shfl(myidx, j + u);
            if constexpr (VPL == 4) {
                ushort4 v[8];
#pragma unroll
                for (int u = 0; u < 8; ++u) v[u] = *(const ushort4*)(hp + (size_t)s[u] * D);
#pragma unroll
                for (int u = 0; u < 8; ++u) {
                    acc[0] += bf2f(v[u].x); acc[1] += bf2f(v[u].y);
                    acc[2] += bf2f(v[u].z); acc[3] += bf2f(v[u].w);
                }
            } else {
                ushort2 v[8];
#pragma unroll
                for (int u = 0; u < 8; ++u) v[u] = *(const ushort2*)(hp + (size_t)s[u] * D);
#pragma unroll
                for (int u = 0; u < 8; ++u) {
                    acc[0] += bf2f(v[u].x); acc[1] += bf2f(v[u].y);
                }
            }
        }
        for (; j + 4 <= n; j += 4) {
            int s[4];
#pragma unroll
            for (int u = 0; u < 4; ++u) s[u] = __shfl(myidx, j + u);
            if constexpr (VPL == 4) {
                ushort4 v[4];
#pragma unroll
                for (int u = 0; u < 4; ++u) v[u] = *(const ushort4*)(hp + (size_t)s[u] * D);
#pragma unroll
                for (int u = 0; u < 4; ++u) {
                    acc[0] += bf2f(v[u].x); acc[1] += bf2f(v[u].y);
                    acc[2] += bf2f(v[u].z); acc[3] += bf2f(v[u].w);
                }
            } else {
                ushort2 v[4];
#pragma unroll
                for (int u = 0; u < 4; ++u) v[u] = *(const ushort2*)(hp + (size_t)s[u] * D);
#pragma unroll
                for (int u = 0; u < 4; ++u) {
                    acc[0] += bf2f(v[u].x); acc[1] += bf2f(v[u].y);
                }
            }
        }
        for (; j < n; ++j) {
            int s = __shfl(myidx, j);
            if constexpr (VPL == 4) {
                ushort4 v = *(const ushort4*)(hp + (size_t)s * D);
                acc[0] += bf2f(v.x); acc[1] += bf2f(v.y);
                acc[2] += bf2f(v.z); acc[3] += bf2f(v.w);
            } else {
                ushort2 v = *(const ushort2*)(hp + (size_t)s * D);
                acc[0] += bf2f(v.x); acc[1] += bf2f(v.y);
            }
        }
    }
    float inv = (end > beg) ? 1.0f / (float)(end - beg) : 0.0f;
    unsigned short* o = mean + (size_t)node * D + lane * VPL;
    if constexpr (VPL == 4) {
        ushort4 r;
        r.x = f2bf(acc[0] * inv); r.y = f2bf(acc[1] * inv);
        r.z = f2bf(acc[2] * inv); r.w = f2bf(acc[3] * inv);
        *(ushort4*)o = r;
    } else {
        ushort2 r;
        r.x = f2bf(acc[0] * inv); r.y = f2bf(acc[1] * inv);
        *(ushort2*)o = r;
    }
}

// ---------------- layer-3 P aggregation ----------------
__global__ void agg_p_kernel(const unsigned short* __restrict__ P,
                             const int* __restrict__ rowptr,
                             const unsigned short* __restrict__ eidx,
                             float* __restrict__ out) {
    const int node = blockIdx.x * (blockDim.x >> 6) + (threadIdx.x >> 6);
    if (node >= NNODES) return;
    const int lane = threadIdx.x & 63;
    const int beg = rowptr[node], end = rowptr[node + 1];
    const bool active = lane < 48;
    const int lc = active ? lane : 0;

    float acc = 0.0f;
    for (int base = beg; base < end; base += 64) {
        int n = min(64, end - base);
        int myidx = (base + lane < end) ? (int)eidx[base + lane] : 0;
        int j = 0;
        for (; j + 4 <= n; j += 4) {
            int s0 = __shfl(myidx, j);
            int s1 = __shfl(myidx, j + 1);
            int s2 = __shfl(myidx, j + 2);
            int s3 = __shfl(myidx, j + 3);
            if (active) {
                float a = bf2f(P[(size_t)s0 * 48 + lc]) + bf2f(P[(size_t)s1 * 48 + lc]);
                float b = bf2f(P[(size_t)s2 * 48 + lc]) + bf2f(P[(size_t)s3 * 48 + lc]);
                acc += a + b;
            }
        }
        for (; j < n; ++j) {
            int s = __shfl(myidx, j);
            if (active) acc += bf2f(P[(size_t)s * 48 + lc]);
        }
    }
    if (lane < 47 && end > beg) {
        out[(size_t)node * DOUT + lane] += acc / (float)(end - beg);
    }
}

// ---------------- bf16 MFMA GEMM ----------------
// MODE 0: A = [H | Mn] virtual concat, K = 2*d, out bf16 [M][N] relu+bias.
// MODE 2: A = H row stride K (d = K/2), dual out: col<47 -> f32 out + bias;
//         col in [47,94) -> Pout bf16 [M][48].
template <int MODE>
__launch_bounds__(256, 2)
__global__ void gemm_mfma_kernel(const unsigned short* __restrict__ H,
                                 const unsigned short* __restrict__ Mn,
                                 const unsigned short* __restrict__ Wt,
                                 const float* __restrict__ bias,
                                 void* __restrict__ outp,
                                 unsigned short* __restrict__ Pout,
                                 int d, int N) {
    const int K = 2 * d;
    __shared__ uint4 AsB[128 * 4];
    __shared__ uint4 BsB[128 * 4];

    const int tid = threadIdx.x;
    const int lane = tid & 63;
    const int wid = tid >> 6;
    const int wr = wid >> 1, wc = wid & 1;
    const int row0 = blockIdx.x * 128;
    const int col0 = blockIdx.y * 128;

    const int sr = tid >> 1;
    const int sh = tid & 1;
    const int gar = min(row0 + sr, NNODES - 1);
    const int gbr = min(col0 + sr, N - 1);
    const int ssw = (sr >> 1) & 3;

    f32x4 acc[4][4];
#pragma unroll
    for (int m = 0; m < 4; ++m)
#pragma unroll
        for (int n = 0; n < 4; ++n) {
            f32x4 z = {0.0f, 0.0f, 0.0f, 0.0f};
            acc[m][n] = z;
        }

    for (int k0 = 0; k0 < K; k0 += 32) {
        {
            int kb = k0 + sh * 16;
            const unsigned short* p;
            if (MODE == 2) {
                p = H + (size_t)gar * K + kb;
            } else {
                p = (kb < d) ? (H + (size_t)gar * d + kb)
                             : (Mn + (size_t)gar * d + (kb - d));
            }
            uint4 v0 = *(const uint4*)p;
            uint4 v1 = *(const uint4*)(p + 8);
            AsB[sr * 4 + ((2 * sh) ^ ssw)]     = v0;
            AsB[sr * 4 + ((2 * sh + 1) ^ ssw)] = v1;
        }
        {
            const unsigned short* p = Wt + (size_t)gbr * K + k0 + sh * 16;
            uint4 v0 = *(const uint4*)p;
            uint4 v1 = *(const uint4*)(p + 8);
            BsB[sr * 4 + ((2 * sh) ^ ssw)]     = v0;
            BsB[sr * 4 + ((2 * sh + 1) ^ ssw)] = v1;
        }
        __syncthreads();

        short8 af[4], bfr[4];
        const int fr = lane & 15;
        const int slot = lane >> 4;
#pragma unroll
        for (int m = 0; m < 4; ++m) {
            int r = wr * 64 + m * 16 + fr;
            union { uint4 u; short8 s; } cc;
            cc.u = AsB[r * 4 + (slot ^ ((r >> 1) & 3))];
            af[m] = cc.s;
        }
#pragma unroll
        for (int n = 0; n < 4; ++n) {
            int r = wc * 64 + n * 16 + fr;
            union { uint4 u; short8 s; } cc;
            cc.u = BsB[r * 4 + (slot ^ ((r >> 1) & 3))];
            bfr[n] = cc.s;
        }
#pragma unroll
        for (int m = 0; m < 4; ++m)
#pragma unroll
            for (int n = 0; n < 4; ++n)
                acc[m][n] = __builtin_amdgcn_mfma_f32_16x16x32_bf16(af[m], bfr[n], acc[m][n], 0, 0, 0);
        __syncthreads();
    }

#pragma unroll
    for (int m = 0; m < 4; ++m) {
#pragma unroll
        for (int n = 0; n < 4; ++n) {
            int col = col0 + wc * 64 + n * 16 + (lane & 15);
            if (col >= N) continue;
            float bv = (MODE == 0) ? bias[col] : ((col < 47) ? bias[col] : 0.0f);
#pragma unroll
            for (int q = 0; q < 4; ++q) {
                int row = row0 + wr * 64 + m * 16 + (lane >> 4) * 4 + q;
                if (row < NNODES) {
                    float v = acc[m][n][q] + bv;
                    if (MODE == 0) {
                        v = fmaxf(v, 0.0f);
                        ((unsigned short*)outp)[(size_t)row * N + col] = f2bf(v);
                    } else {
                        if (col < 47) ((float*)outp)[(size_t)row * DOUT + col] = v;
                        else Pout[(size_t)row * 48 + (col - 47)] = f2bf(v);
                    }
                }
            }
        }
    }
}

extern "C" void kernel_launch(void* const* d_in, const int* in_sizes, int n_in,
                              void* d_out, int out_size, void* d_ws, size_t ws_size,
                              hipStream_t stream) {
    const float* x  = (const float*)d_in[0];
    const float* W1 = (const float*)d_in[1];
    const float* b1 = (const float*)d_in[2];
    const float* W2 = (const float*)d_in[3];
    const float* b2 = (const float*)d_in[4];
    const float* W3 = (const float*)d_in[5];
    const float* b3 = (const float*)d_in[6];
    const int* src  = (const int*)d_in[7];
    const int* dst  = (const int*)d_in[8];
    float* out = (float*)d_out;

    int* rowptr  = (int*)d_ws;                          // NCNT ints
    unsigned short* eidx = (unsigned short*)(rowptr + NCNT);  // NEDGES ushort
    int* cnt     = (int*)(eidx + NEDGES);               // NCNT
    int* fill    = cnt + NCNT;                          // NCNT
    int* part    = fill + NCNT;                         // 256
    int* partoff = part + 256;                          // 256
    unsigned short* xbf  = (unsigned short*)(partoff + 256);
    unsigned short* h1   = xbf + (size_t)NNODES * DIN;
    unsigned short* h2   = h1 + (size_t)NNODES * DHID;
    unsigned short* mean = h2 + (size_t)NNODES * DHID;
    unsigned short* wt1  = mean + (size_t)NNODES * DHID;
    unsigned short* wt2  = wt1 + 2 * DIN * DHID;
    unsigned short* wt3  = wt2 + 2 * DHID * DHID;
    unsigned short* P    = mean;  // layer-3 reuse

    // ---- CSR build ----
    hipMemsetAsync(cnt, 0, 2 * NCNT * sizeof(int), stream);
    hist_kernel<<<(NEDGES + 255) / 256, 256, 0, stream>>>(dst, cnt);
    part_kernel<<<NPART, 256, 0, stream>>>(cnt, part);
    scanpart_kernel<<<1, 256, 0, stream>>>(part, partoff);
    writeptr_kernel<<<NPART, 256, 0, stream>>>(cnt, partoff, rowptr);
    fill_kernel<<<(NEDGES + 255) / 256, 256, 0, stream>>>(src, dst, rowptr, fill, eidx);

    // ---- conversions ----
    f32_to_bf16x4_kernel<<<(NNODES * DIN / 4 + 255) / 256, 256, 0, stream>>>(
        (const float4*)x, (ushort4*)xbf, NNODES * DIN / 4);
    conv_wt_kernel<<<(2 * DIN * DHID + 255) / 256, 256, 0, stream>>>(W1, wt1, 2 * DIN, DHID);
    conv_wt_kernel<<<(2 * DHID * DHID + 255) / 256, 256, 0, stream>>>(W2, wt2, 2 * DHID, DHID);
    conv_wt3_kernel<<<(94 * 256 + 255) / 256, 256, 0, stream>>>(W3, wt3);

    const int MB = (NNODES + 127) / 128;  // 313

    // ---- layer 1: d=128 -> 256
    agg_bf16_kernel<DIN><<<NNODES / 4, 256, 0, stream>>>(xbf, rowptr, eidx, mean);
    {
        dim3 grid(MB, 2);
        gemm_mfma_kernel<0><<<grid, 256, 0, stream>>>(xbf, mean, wt1, b1, h1, nullptr, DIN, DHID);
    }

    // ---- layer 2: d=256 -> 256
    agg_bf16_kernel<DHID><<<NNODES / 4, 256, 0, stream>>>(h1, rowptr, eidx, mean);
    {
        dim3 grid(MB, 2);
        gemm_mfma_kernel<0><<<grid, 256, 0, stream>>>(h1, mean, wt2, b2, h2, nullptr, DHID, DHID);
    }

    // ---- layer 3: dual GEMM then P-aggregate
    {
        dim3 grid(MB, 1);
        gemm_mfma_kernel<2><<<grid, 256, 0, stream>>>(h2, h2, wt3, b3, out, P, DHID / 2, 94);
    }
    agg_p_kernel<<<NNODES / 4, 256, 0, stream>>>(P, rowptr, eidx, out);
}